// Round 6
// baseline (339.992 us; speedup 1.0000x reference)
//
#include <hip/hip_runtime.h>

#define NSEG   4194304
#define BLOCK  256
#define TILE   4096                // per block per curve
#define CHUNK  1024                // per scan pass (BLOCK * 4)
#define NCHUNK 4
#define NTILES 1024                // == gridDim.x; 4 blocks/CU * 256 CU
#define WAVES  (BLOCK / 64)
#define POISON 0xAAAAAAAAu         // harness re-poisons ws to 0xAA every launch

static_assert(NTILES * TILE == NSEG, "tiling must cover N");

// Segment monoid: T = sum of angles, C/S = sum of cos/sin of segment-local
// inclusive cumulative angle. combine(a,b) = "a followed by b". Identity 0.
__device__ __forceinline__ void combineSeg(float aT, float aC, float aS,
                                           float bT, float bC, float bS,
                                           float& oT, float& oC, float& oS) {
    float s, c;
    __sincosf(aT, &s, &c);
    oT = aT + bT;
    oC = aC + c * bC - s * bS;
    oS = aS + s * bC + c * bS;
}

// One kernel, software grid barrier. 1024 blocks x 256 thr, VGPR<=128 via
// launch_bounds -> 4 blocks/CU -> all 1024 co-resident -> no deadlock.
__global__ __launch_bounds__(BLOCK, 4) void k_all(
        const float* __restrict__ vec, const float* __restrict__ vec2,
        const float* __restrict__ the0, const float* __restrict__ the02,
        const float* __restrict__ PS, const float* __restrict__ PE,
        const float* __restrict__ dl,
        unsigned int* __restrict__ cnt, float4* __restrict__ part,
        float* __restrict__ out) {
    const int b = blockIdx.x;
    const int t = threadIdx.x;
    const int lane = t & 63, wave = t >> 6;

    __shared__ float sA[2][NCHUNK][WAVES];
    __shared__ float sCx[2][NCHUNK][WAVES], sCy[2][NCHUNK][WAVES];
    __shared__ float sMT[WAVES], sMC[WAVES], sMS[WAVES];
    __shared__ float sPre[2][3];

    float4 a[2][NCHUNK];           // all inputs, held in regs across barrier
    float exC[2][NCHUNK], exS[2][NCHUNK], bAng[2][NCHUNK];

    // ================= Phase 1: per-tile scans with LOCAL angles =============
#pragma unroll
    for (int c = 0; c < 2; ++c) {
        const float* __restrict__ v = c ? vec2 : vec;
        const float4* __restrict__ p =
            reinterpret_cast<const float4*>(v + (size_t)b * TILE);
#pragma unroll
        for (int g = 0; g < NCHUNK; ++g) a[c][g] = p[g * (CHUNK / 4) + t];

        float runT = 0.f, carC = 0.f, carS = 0.f;
#pragma unroll
        for (int g = 0; g < NCHUNK; ++g) {
            const float v0 = a[c][g].x, v1 = a[c][g].y,
                        v2 = a[c][g].z, v3 = a[c][g].w;
            const float s4 = v0 + v1 + v2 + v3;
            float incl = s4;
#pragma unroll
            for (int d = 1; d < 64; d <<= 1) {
                float o = __shfl_up(incl, d, 64);
                if (lane >= d) incl += o;
            }
            if (lane == 63) sA[c][g][wave] = incl;
            __syncthreads();
            float wpre = 0.f, totA = 0.f;
#pragma unroll
            for (int w = 0; w < WAVES; ++w) {
                float x = sA[c][g][w];
                if (w < wave) wpre += x;
                totA += x;
            }
            bAng[c][g] = runT + wpre + incl - s4;  // tile-local angle base
            float run = bAng[c][g];
            float cs0, sn0, cs1, sn1, cs2, sn2, cs3, sn3;
            run += v0; __sincosf(run, &sn0, &cs0);
            run += v1; __sincosf(run, &sn1, &cs1);
            run += v2; __sincosf(run, &sn2, &cs2);
            run += v3; __sincosf(run, &sn3, &cs3);
            const float oC = cs0 + cs1 + cs2 + cs3;
            const float oS = sn0 + sn1 + sn2 + sn3;
            float ix = oC, iy = oS;
#pragma unroll
            for (int d = 1; d < 64; d <<= 1) {
                float ox = __shfl_up(ix, d, 64);
                float oy = __shfl_up(iy, d, 64);
                if (lane >= d) { ix += ox; iy += oy; }
            }
            if (lane == 63) { sCx[c][g][wave] = ix; sCy[c][g][wave] = iy; }
            __syncthreads();
            float wpx = 0.f, wpy = 0.f, totC = 0.f, totS = 0.f;
#pragma unroll
            for (int w = 0; w < WAVES; ++w) {
                float xx = sCx[c][g][w], yy = sCy[c][g][w];
                if (w < wave) { wpx += xx; wpy += yy; }
                totC += xx; totS += yy;
            }
            exC[c][g] = carC + wpx + ix - oC;   // local cos-prefix incl. carry
            exS[c][g] = carS + wpy + iy - oS;
            runT += totA; carC += totC; carS += totS;
        }
        // runT/carC/carS are block-uniform -> tile summary
        if (t == 0) part[c * NTILES + b] = make_float4(runT, carC, carS, 0.f);
    }

    // ================= Software grid barrier =================
    if (t == 0) {
        __threadfence();                        // make part[] device-visible
        atomicAdd(cnt, 1u);                     // device-scope by default
        while (__hip_atomic_load(cnt, __ATOMIC_ACQUIRE,
                                 __HIP_MEMORY_SCOPE_AGENT)
               != POISON + (unsigned)NTILES)
            __builtin_amdgcn_s_sleep(8);
    }
    __syncthreads();
    __threadfence();                            // L1 invalidate before reads

    // ============ Phase A: redundant scan of tile summaries (per curve) ======
#pragma unroll
    for (int c = 0; c < 2; ++c) {
        const float4* __restrict__ pp = part + (size_t)c * NTILES;
        float aT[4], aC[4], aS[4];
        float T = 0.f, C = 0.f, S = 0.f;
#pragma unroll
        for (int j = 0; j < 4; ++j) {
            float4 d4 = pp[t * 4 + j];
            aT[j] = d4.x; aC[j] = d4.y; aS[j] = d4.z;
            combineSeg(T, C, S, aT[j], aC[j], aS[j], T, C, S);
        }
        float iT = T, iC = C, iS = S;
#pragma unroll
        for (int d = 1; d < 64; d <<= 1) {
            float oT = __shfl_up(iT, d, 64);
            float oC = __shfl_up(iC, d, 64);
            float oS = __shfl_up(iS, d, 64);
            if (lane >= d) combineSeg(oT, oC, oS, iT, iC, iS, iT, iC, iS);
        }
        float pT = __shfl_up(iT, 1, 64);
        float pC = __shfl_up(iC, 1, 64);
        float pS = __shfl_up(iS, 1, 64);
        float eT = (lane == 0) ? 0.f : pT;
        float eC2 = (lane == 0) ? 0.f : pC;
        float eS2 = (lane == 0) ? 0.f : pS;
        __syncthreads();                        // protect sMT reuse (c=1)
        if (lane == 63) { sMT[wave] = iT; sMC[wave] = iC; sMS[wave] = iS; }
        __syncthreads();
        float wT = 0.f, wC = 0.f, wS = 0.f;
#pragma unroll
        for (int w = 0; w < WAVES; ++w) {
            if (w < wave) combineSeg(wT, wC, wS, sMT[w], sMC[w], sMS[w], wT, wC, wS);
        }
        float xT, xC, xS;                       // exclusive over tiles < 4t
        combineSeg(wT, wC, wS, eT, eC2, eS2, xT, xC, xS);

        if (b == 0) {
            if (t == 0) { sPre[c][0] = 0.f; sPre[c][1] = 0.f; sPre[c][2] = 0.f; }
        } else {
            const int q = (b - 1) >> 2;
            if (t == q) {
                float PT = xT, PC = xC, PZ = xS;
                const int m = (b - 1) & 3;
                for (int j = 0; j <= m; ++j)
                    combineSeg(PT, PC, PZ, aT[j], aC[j], aS[j], PT, PC, PZ);
                sPre[c][0] = PT; sPre[c][1] = PC; sPre[c][2] = PZ;
            }
        }
    }
    __syncthreads();

    // ============ Phase 3: rotate local prefixes, emit (no scans/barriers) ===
    const float dlv = dl[0];
#pragma unroll
    for (int c = 0; c < 2; ++c) {
        const float t0 = c ? the02[0] : the0[0];
        const float sx = c ? PE[0] : PS[0];
        const float sy = c ? PE[1] : PS[1];
        float s0, c0;
        __sincosf(t0, &s0, &c0);
        const float thPre = t0 + sPre[c][0];
        const float pxB = sx + dlv * (c0 * sPre[c][1] - s0 * sPre[c][2]);
        const float pyB = sy + dlv * (s0 * sPre[c][1] + c0 * sPre[c][2]);
        float sp, cp;
        __sincosf(thPre, &sp, &cp);

        float2* __restrict__ o2 =
            reinterpret_cast<float2*>(out) + (size_t)c * (NSEG + 1);
#pragma unroll
        for (int g = 0; g < NCHUNK; ++g) {
            const float v0 = a[c][g].x, v1 = a[c][g].y,
                        v2 = a[c][g].z, v3 = a[c][g].w;
            // rotate local (cos,sin) prefix into global frame
            float px = pxB + dlv * (cp * exC[c][g] - sp * exS[c][g]);
            float py = pyB + dlv * (sp * exC[c][g] + cp * exS[c][g]);
            float run = thPre + bAng[c][g];
            float cs0, sn0, cs1, sn1, cs2, sn2, cs3, sn3;
            run += v0; __sincosf(run, &sn0, &cs0);
            run += v1; __sincosf(run, &sn1, &cs1);
            run += v2; __sincosf(run, &sn2, &cs2);
            run += v3; __sincosf(run, &sn3, &cs3);
            const size_t idx0 = (size_t)b * TILE + (size_t)g * CHUNK + 4 * t;
            o2[idx0 + 0] = make_float2(px, py);
            px += dlv * cs0; py += dlv * sn0;
            o2[idx0 + 1] = make_float2(px, py);
            px += dlv * cs1; py += dlv * sn1;
            o2[idx0 + 2] = make_float2(px, py);
            px += dlv * cs2; py += dlv * sn2;
            o2[idx0 + 3] = make_float2(px, py);
            if (g == NCHUNK - 1 && b == NTILES - 1 && t == BLOCK - 1) {
                px += dlv * cs3; py += dlv * sn3;
                o2[NSEG] = make_float2(px, py);   // final point
            }
        }
    }
}

extern "C" void kernel_launch(void* const* d_in, const int* in_sizes, int n_in,
                              void* d_out, int out_size, void* d_ws, size_t ws_size,
                              hipStream_t stream) {
    const float* vec   = (const float*)d_in[0];
    const float* vec2  = (const float*)d_in[1];
    const float* the0  = (const float*)d_in[2];
    const float* the02 = (const float*)d_in[3];
    const float* PS    = (const float*)d_in[4];
    const float* PE    = (const float*)d_in[5];
    const float* dl    = (const float*)d_in[6];
    float* out = (float*)d_out;

    // ws: [0] barrier counter (poisoned 0xAAAAAAAA each launch -> target =
    // POISON + NTILES); +4KB: part float4[2*1024] = 32 KB.
    char* wsb = (char*)d_ws;
    unsigned int* cnt = (unsigned int*)wsb;
    float4* part = (float4*)(wsb + 4096);

    k_all<<<dim3(NTILES), BLOCK, 0, stream>>>(
        vec, vec2, the0, the02, PS, PE, dl, cnt, part, out);
}

// Round 7
// 260.073 us; speedup vs baseline: 1.3073x; 1.3073x over previous
//
#include <hip/hip_runtime.h>

#define NSEG   4194304
#define BLOCK  256
#define TILE   4096                // per block per curve
#define CHUNK  1024                // per scan pass (BLOCK * 4)
#define NCHUNK 4
#define NTILES 1024                // == gridDim.x; 4 blocks/CU * 256 CUs
#define WAVES  (BLOCK / 64)
#define POISON 0xAAAAAAAAu         // ws poison value each launch

static_assert(NTILES * TILE == NSEG, "tiling must cover N");

// Segment monoid: T = sum of angles, C/S = sum of cos/sin of segment-local
// inclusive cumulative angle. combine(a,b) = "a followed by b". Identity 0.
__device__ __forceinline__ void combineSeg(float aT, float aC, float aS,
                                           float bT, float bC, float bS,
                                           float& oT, float& oC, float& oS) {
    float s, c;
    __sincosf(aT, &s, &c);
    oT = aT + bT;
    oC = aC + c * bC - s * bS;
    oS = aS + s * bC + c * bS;
}

// Single kernel, software grid barrier. Cross-barrier state lives in LDS
// (32 KB angle array), NOT registers -> no spills (round-6 failure mode).
// LDS 32.9 KB/block -> 4 blocks/CU -> 1024 blocks co-resident -> no deadlock.
__global__ __launch_bounds__(BLOCK)
__attribute__((amdgpu_waves_per_eu(4, 4)))
void k_all(const float* __restrict__ vec, const float* __restrict__ vec2,
           const float* __restrict__ the0, const float* __restrict__ the02,
           const float* __restrict__ PS, const float* __restrict__ PE,
           const float* __restrict__ dl,
           unsigned int* __restrict__ cnt, float4* __restrict__ part,
           float* __restrict__ out) {
    const int b = blockIdx.x;
    const int t = threadIdx.x;
    const int lane = t & 63, wave = t >> 6;

    __shared__ __align__(16) float sAng[2][TILE];   // 32 KB: local incl. angles
    __shared__ float sSc[WAVES];
    __shared__ float sSx[WAVES], sSy[WAVES];
    __shared__ float sMT[WAVES], sMC[WAVES], sMS[WAVES];
    __shared__ float sPre[2][3];

    // ================= Phase 1: per-tile angle scan + (T,C,S) reduction ======
#pragma unroll
    for (int c = 0; c < 2; ++c) {
        const float* __restrict__ v = c ? vec2 : vec;
        const float4* __restrict__ p =
            reinterpret_cast<const float4*>(v + (size_t)b * TILE);
        float4 a[NCHUNK];
#pragma unroll
        for (int g = 0; g < NCHUNK; ++g) a[g] = p[g * (CHUNK / 4) + t];

        float runT = 0.f, accC = 0.f, accS = 0.f;
#pragma unroll
        for (int g = 0; g < NCHUNK; ++g) {
            const float v0 = a[g].x, v1 = a[g].y, v2 = a[g].z, v3 = a[g].w;
            const float s4 = v0 + v1 + v2 + v3;
            float incl = s4;
#pragma unroll
            for (int d = 1; d < 64; d <<= 1) {
                float o = __shfl_up(incl, d, 64);
                if (lane >= d) incl += o;
            }
            if (lane == 63) sSc[wave] = incl;
            __syncthreads();
            float wpre = 0.f, tot = 0.f;
#pragma unroll
            for (int w = 0; w < WAVES; ++w) {
                float x = sSc[w];
                if (w < wave) wpre += x;
                tot += x;
            }
            float run = runT + wpre + incl - s4;   // local angle before elem 0
            float sn, cs;
            float r0, r1, r2, r3;
            run += v0; r0 = run; __sincosf(run, &sn, &cs); accC += cs; accS += sn;
            run += v1; r1 = run; __sincosf(run, &sn, &cs); accC += cs; accS += sn;
            run += v2; r2 = run; __sincosf(run, &sn, &cs); accC += cs; accS += sn;
            run += v3; r3 = run; __sincosf(run, &sn, &cs); accC += cs; accS += sn;
            reinterpret_cast<float4*>(&sAng[c][g * CHUNK])[t] =
                make_float4(r0, r1, r2, r3);       // state for phase 3
            runT += tot;
            __syncthreads();                        // protect sSc reuse
        }
        // block reduction of (accC, accS); runT already block-uniform
#pragma unroll
        for (int d = 32; d > 0; d >>= 1) {
            accC += __shfl_down(accC, d, 64);
            accS += __shfl_down(accS, d, 64);
        }
        if (lane == 0) { sSx[wave] = accC; sSy[wave] = accS; }
        __syncthreads();
        if (t == 0) {
            float Ct = 0.f, St = 0.f;
#pragma unroll
            for (int w = 0; w < WAVES; ++w) { Ct += sSx[w]; St += sSy[w]; }
            part[c * NTILES + b] = make_float4(runT, Ct, St, 0.f);
        }
        __syncthreads();                            // protect sSx reuse
    }

    // ================= Software grid barrier (validated in round 6) ==========
    if (t == 0) {
        __threadfence();                            // make part[] visible
        atomicAdd(cnt, 1u);                         // device-scope default
        while (__hip_atomic_load(cnt, __ATOMIC_ACQUIRE,
                                 __HIP_MEMORY_SCOPE_AGENT)
               != POISON + (unsigned)NTILES)
            __builtin_amdgcn_s_sleep(8);
    }
    __syncthreads();
    __threadfence();                                // invalidate L1 before reads

    // ============ Phase A: redundant scan of tile summaries (per curve) ======
#pragma unroll
    for (int c = 0; c < 2; ++c) {
        const float4* __restrict__ pp = part + (size_t)c * NTILES;
        float aT[4], aC[4], aS[4];
        float T = 0.f, C = 0.f, S = 0.f;
#pragma unroll
        for (int j = 0; j < 4; ++j) {
            float4 d4 = pp[t * 4 + j];
            aT[j] = d4.x; aC[j] = d4.y; aS[j] = d4.z;
            combineSeg(T, C, S, aT[j], aC[j], aS[j], T, C, S);
        }
        float iT = T, iC = C, iS = S;
#pragma unroll
        for (int d = 1; d < 64; d <<= 1) {
            float oT = __shfl_up(iT, d, 64);
            float oC = __shfl_up(iC, d, 64);
            float oS = __shfl_up(iS, d, 64);
            if (lane >= d) combineSeg(oT, oC, oS, iT, iC, iS, iT, iC, iS);
        }
        float pT = __shfl_up(iT, 1, 64);
        float pC = __shfl_up(iC, 1, 64);
        float pS = __shfl_up(iS, 1, 64);
        float eT = (lane == 0) ? 0.f : pT;
        float eC = (lane == 0) ? 0.f : pC;
        float eS = (lane == 0) ? 0.f : pS;
        __syncthreads();                            // sMT write-after-read
        if (lane == 63) { sMT[wave] = iT; sMC[wave] = iC; sMS[wave] = iS; }
        __syncthreads();
        float wT = 0.f, wC = 0.f, wS = 0.f;
#pragma unroll
        for (int w = 0; w < WAVES; ++w) {
            if (w < wave) combineSeg(wT, wC, wS, sMT[w], sMC[w], sMS[w], wT, wC, wS);
        }
        float xT, xC, xS;                           // exclusive over tiles < 4t
        combineSeg(wT, wC, wS, eT, eC, eS, xT, xC, xS);

        if (b == 0) {
            if (t == 0) { sPre[c][0] = 0.f; sPre[c][1] = 0.f; sPre[c][2] = 0.f; }
        } else {
            const int q = (b - 1) >> 2;
            if (t == q) {
                float PT = xT, PC = xC, PZ = xS;
                const int m = (b - 1) & 3;
                for (int j = 0; j <= m; ++j)
                    combineSeg(PT, PC, PZ, aT[j], aC[j], aS[j], PT, PC, PZ);
                sPre[c][0] = PT; sPre[c][1] = PC; sPre[c][2] = PZ;
            }
        }
    }
    __syncthreads();

    // ============ Phase 3: absolute angles from LDS -> sincos -> emit ========
    const float dlv = dl[0];
#pragma unroll
    for (int c = 0; c < 2; ++c) {
        const float t0 = c ? the02[0] : the0[0];
        const float sx = c ? PE[0] : PS[0];
        const float sy = c ? PE[1] : PS[1];
        float s0, c0;
        __sincosf(t0, &s0, &c0);
        const float thPre = t0 + sPre[c][0];
        const float pxB = sx + dlv * (c0 * sPre[c][1] - s0 * sPre[c][2]);
        const float pyB = sy + dlv * (s0 * sPre[c][1] + c0 * sPre[c][2]);

        float4* __restrict__ o4 =
            reinterpret_cast<float4*>(out + (size_t)c * (NSEG + 1) * 2);
        float carC = 0.f, carS = 0.f;
#pragma unroll
        for (int g = 0; g < NCHUNK; ++g) {
            const float4 r =
                reinterpret_cast<const float4*>(&sAng[c][g * CHUNK])[t];
            float cs[4], sn[4];
            __sincosf(thPre + r.x, &sn[0], &cs[0]);  // absolute -> global frame
            __sincosf(thPre + r.y, &sn[1], &cs[1]);
            __sincosf(thPre + r.z, &sn[2], &cs[2]);
            __sincosf(thPre + r.w, &sn[3], &cs[3]);
            const float sC4 = cs[0] + cs[1] + cs[2] + cs[3];
            const float sS4 = sn[0] + sn[1] + sn[2] + sn[3];
            float ix = sC4, iy = sS4;
#pragma unroll
            for (int d = 1; d < 64; d <<= 1) {
                float ox = __shfl_up(ix, d, 64);
                float oy = __shfl_up(iy, d, 64);
                if (lane >= d) { ix += ox; iy += oy; }
            }
            if (lane == 63) { sSx[wave] = ix; sSy[wave] = iy; }
            __syncthreads();
            float wpx = 0.f, wpy = 0.f, totC = 0.f, totS = 0.f;
#pragma unroll
            for (int w = 0; w < WAVES; ++w) {
                float xx = sSx[w], yy = sSy[w];
                if (w < wave) { wpx += xx; wpy += yy; }
                totC += xx; totS += yy;
            }
            const float x0 = pxB + dlv * (carC + wpx + ix - sC4);
            const float y0 = pyB + dlv * (carS + wpy + iy - sS4);
            const float x1 = x0 + dlv * cs[0], y1 = y0 + dlv * sn[0];
            const float x2 = x1 + dlv * cs[1], y2 = y1 + dlv * sn[1];
            const float x3 = x2 + dlv * cs[2], y3 = y2 + dlv * sn[2];
            carC += totC; carS += totS;

            const size_t obase =
                ((size_t)b * TILE + (size_t)g * CHUNK) / 2 + 2 * t;
            o4[obase + 0] = make_float4(x0, y0, x1, y1);
            o4[obase + 1] = make_float4(x2, y2, x3, y3);

            if (g == NCHUNK - 1 && b == NTILES - 1 && t == BLOCK - 1) {
                reinterpret_cast<float2*>(
                    out + (size_t)c * (NSEG + 1) * 2)[NSEG] =
                    make_float2(x3 + dlv * cs[3], y3 + dlv * sn[3]);
            }
            __syncthreads();                        // protect sSx reuse
        }
    }
}

extern "C" void kernel_launch(void* const* d_in, const int* in_sizes, int n_in,
                              void* d_out, int out_size, void* d_ws, size_t ws_size,
                              hipStream_t stream) {
    const float* vec   = (const float*)d_in[0];
    const float* vec2  = (const float*)d_in[1];
    const float* the0  = (const float*)d_in[2];
    const float* the02 = (const float*)d_in[3];
    const float* PS    = (const float*)d_in[4];
    const float* PE    = (const float*)d_in[5];
    const float* dl    = (const float*)d_in[6];
    float* out = (float*)d_out;

    // ws: [0] barrier counter (poisoned 0xAAAAAAAA -> target POISON + NTILES);
    // +4KB: part float4[2*1024] = 32 KB.
    char* wsb = (char*)d_ws;
    unsigned int* cnt = (unsigned int*)wsb;
    float4* part = (float4*)(wsb + 4096);

    k_all<<<dim3(NTILES), BLOCK, 0, stream>>>(
        vec, vec2, the0, the02, PS, PE, dl, cnt, part, out);
}